// Round 10
// baseline (36.630 us; speedup 1.0000x reference)
//
#include <hip/hip_runtime.h>

// HighOrderActivationB, round 9: LDS-staged gathers + full occupancy.
// r7 confirmed TA-saturation theory (67.5 -> 36.4 us via LDS gathers).
// r9: GC 32->16 halves LDS (14080 B) -> 8 blocks/CU = 32 waves/CU (was 16),
// plus unroll-4 main loop for cross-iteration load ILP.
// Staging total unchanged (grid.y * 0.88 MB = 28 MB).

#define B_BATCH 4096
#define N_GROUPS 1024
#define N_TERMS 27
#define OUT_DIM 8
#define GC 16           // groups per block
#define BC 128          // batch rows per block
#define ROW_STRIDE 220  // dwords: %32==28 -> 8 distinct bank starts; *4%16==0 (b128 aligned)

typedef float floatx4 __attribute__((ext_vector_type(4)));

__global__ __launch_bounds__(256)
void hoa_kernel(const float* __restrict__ X,
                const float* __restrict__ P,
                float* __restrict__ out) {
    __shared__ float lds[GC * ROW_STRIDE];   // 14080 B

    const int tid = threadIdx.x;
    const int g0 = blockIdx.x * GC;
    const int b0 = blockIdx.y * BC;

    // ---- stage params for GC groups: 16 rows x 54 float4 ----
    {
        const floatx4* P4 = (const floatx4*)(P + (size_t)g0 * (N_TERMS * OUT_DIM));
        floatx4* L4 = (floatx4*)lds;
        for (int i = tid; i < GC * 54; i += 256) {
            const int r = i / 54;
            const int c = i - r * 54;
            L4[r * (ROW_STRIDE / 4) + c] = P4[i];
        }
    }
    __syncthreads();

    const int g_local = tid & (GC - 1);
    const int b_slot = tid >> 4;             // 0..15
    const float* lg = lds + g_local * ROW_STRIDE;
    const int g = g0 + g_local;

    #pragma unroll 4
    for (int it = 0; it < BC / 16; ++it) {   // 8 iterations
        const int b = b0 + b_slot + it * 16;

        // dense X read: wave = 16 consecutive g x 4 b -> 4 x 192B segments
        const float* xp = X + (size_t)b * (N_GROUPS * 3) + g * 3;
        const float A0 = xp[0];
        const float A1 = xp[1];
        const float A2 = xp[2];

        float m0 = fabsf(A0), m1 = fabsf(A1), m2 = fabsf(A2);
        int t0 = (A0 >= 0.0f) ? 1 : -1;
        int t1 = (A1 >= 0.0f) ? 3 : -3;
        int t2 = (A2 >= 0.0f) ? 9 : -9;

        // stable ascending 3-sort by magnitude (strict > = stable)
        if (m0 > m1) { float tm=m0; m0=m1; m1=tm; int tt=t0; t0=t1; t1=tt; }
        if (m1 > m2) { float tm=m1; m1=m2; m2=tm; int tt=t1; t1=t2; t2=tt; }
        if (m0 > m1) { float tm=m0; m0=m1; m1=tm; int tt=t0; t0=t1; t1=tt; }

        const float c0 = m0;
        const float c1 = m1 - m0;
        const float c2 = m2 - m1;

        const int i2 = 13 + t2;
        const int i1 = i2 + t1;
        const int i0 = i1 + t0;

        // LDS gathers: 6x ds_read_b128
        const floatx4* r0 = (const floatx4*)(lg + i0 * OUT_DIM);
        const floatx4* r1 = (const floatx4*)(lg + i1 * OUT_DIM);
        const floatx4* r2 = (const floatx4*)(lg + i2 * OUT_DIM);
        const floatx4 g0a = r0[0], g0b = r0[1];
        const floatx4 g1a = r1[0], g1b = r1[1];
        const floatx4 g2a = r2[0], g2b = r2[1];

        const floatx4 oa = c0 * g0a + c1 * g1a + c2 * g2a;
        const floatx4 ob = c0 * g0b + c1 * g1b + c2 * g2b;

        // dense store: per-lane contiguous 32B; lanes 32B apart; L2 merges
        floatx4* op = (floatx4*)(out + (size_t)b * (N_GROUPS * OUT_DIM) + g * OUT_DIM);
        op[0] = oa;
        op[1] = ob;
    }
}

extern "C" void kernel_launch(void* const* d_in, const int* in_sizes, int n_in,
                              void* d_out, int out_size, void* d_ws, size_t ws_size,
                              hipStream_t stream) {
    const float* X = (const float*)d_in[0];
    const float* P = (const float*)d_in[1];
    float* out = (float*)d_out;

    dim3 grid(N_GROUPS / GC, B_BATCH / BC);   // (64, 32) = 2048 blocks = 8/CU
    hoa_kernel<<<grid, 256, 0, stream>>>(X, P, out);
}